// Round 6
// baseline (184.794 us; speedup 1.0000x reference)
//
#include <hip/hip_runtime.h>

// ---------------------------------------------------------------------------
// HypothesisDecoder: dense-grid trilinear interp + fused fp16-MFMA conv stack
// Round 9: keep r8's split (k_main conv @119us verified) but fix k_interp,
// which cost ~62us of the 184 total:
//   - ONE THREAD PER QUERY (was 2: one per 16-ch part) -> dedup the 8 grid
//     loads, coord math, pdh/batch reads; 32-float accumulator in regs.
//   - DROP the ptsfeat passthrough: Xg holds only the 32 interp channels
//     (25.3MB). k_main's staging reads ptsfeat f32 directly (NT) + cvt --
//     the exact code r5b ran inline. Removes ~75MB from k_interp.
// Expected: k_interp ~15-20us, k_main ~119-127us, total ~140-150us.
// ---------------------------------------------------------------------------
#define GG 96
#define NB 2
#define RESV 0.04f

constexpr int NG  = NB * GG * GG * GG;  // dense voxel grid cells (1,769,472)
constexpr int PT  = 16;                 // points per block
constexpr int NCOLS = PT * 8;           // 128 output columns (7 real + 1 dead per pt)
constexpr int XC  = NCOLS + 2;          // 130 LDS columns
constexpr int CS  = 136;                // LDS stride in halves (272B = 68 dwords)

typedef _Float16 f16x8 __attribute__((ext_vector_type(8)));
typedef _Float16 f16x4 __attribute__((ext_vector_type(4)));
typedef _Float16 f16x2 __attribute__((ext_vector_type(2)));
typedef float    f32x4 __attribute__((ext_vector_type(4)));

// ---------------------------------------------------------------------------
__global__ void k_init(int4* __restrict__ grid4, int* __restrict__ minc) {
    int i = blockIdx.x * 256 + threadIdx.x;
    if (i < NG / 4) grid4[i] = make_int4(0x7fffffff, 0x7fffffff, 0x7fffffff, 0x7fffffff);
    if (i < 6)      minc[i] = 0x7fffffff;
}

__global__ void k_scatter(const int* __restrict__ coords, const int* __restrict__ sbatch,
                          int n, int* __restrict__ grid, int* __restrict__ minc) {
    __shared__ int lmin[6];
    int tid = threadIdx.x;
    if (tid < 6) lmin[tid] = 0x7fffffff;
    __syncthreads();
    int i = blockIdx.x * 256 + tid;
    if (i < n) {
        int cx = coords[3*i], cy = coords[3*i+1], cz = coords[3*i+2];
        int b = sbatch[i];
        // stable-argsort + leftmost searchsorted == keep smallest original index
        atomicMin(&grid[((b*GG + cx)*GG + cy)*GG + cz], i);
        atomicMin(&lmin[b*3+0], cx);
        atomicMin(&lmin[b*3+1], cy);
        atomicMin(&lmin[b*3+2], cz);
    }
    __syncthreads();
    if (tid < 6) atomicMin(&minc[tid], lmin[tid]);
}

// ---------------------------------------------------------------------------
// Weights -> fp16 MFMA-fragment order with BN scale folded in.
// Fragment index: (((mt*KS + ks)*64 + lane)*8 + j) ; element:
//   row = mt*16 + (lane&15), k = ks*32 + (lane>>4)*8 + j, tap = k/CIN, c = k%CIN
// tvec[layer*128 + ch] = b - m * (g / sqrt(v + eps))
__global__ void k_wconv(const float* __restrict__ w1, const float* __restrict__ w2,
                        const float* __restrict__ w3,
                        const float* __restrict__ g1, const float* __restrict__ b1,
                        const float* __restrict__ m1, const float* __restrict__ v1,
                        const float* __restrict__ g2, const float* __restrict__ b2,
                        const float* __restrict__ m2, const float* __restrict__ v2,
                        const float* __restrict__ g3, const float* __restrict__ b3,
                        const float* __restrict__ m3, const float* __restrict__ v3,
                        _Float16* __restrict__ o1, _Float16* __restrict__ o2,
                        _Float16* __restrict__ o3, float* __restrict__ tvec) {
    int e = blockIdx.x * 256 + threadIdx.x;
    if (e < 24576) {                              // layer 1: 128 x 192, KS=6
        int j = e & 7, lane = (e >> 3) & 63, t2 = e >> 9;   // t2 in [0,48)
        int mt = t2 / 6, ks = t2 % 6;
        int row = mt * 16 + (lane & 15);
        int k = ks * 32 + ((lane >> 4) << 3) + j;
        int tap = k >> 6, c = k & 63;
        float s = g1[row] / sqrtf(v1[row] + 1e-5f);
        o1[e] = (_Float16)(w1[(row * 64 + c) * 3 + tap] * s);
    } else if (e < 122880) {                      // layers 2/3: 128 x 384, KS=12
        int u = e - 24576;
        int layer = u / 49152;
        u %= 49152;
        int j = u & 7, lane = (u >> 3) & 63, t2 = u >> 9;   // t2 in [0,96)
        int mt = t2 / 12, ks = t2 % 12;
        int row = mt * 16 + (lane & 15);
        int k = ks * 32 + ((lane >> 4) << 3) + j;
        int tap = k >> 7, c = k & 127;
        const float* w = layer ? w3 : w2;
        const float* g = layer ? g3 : g2;
        const float* v = layer ? v3 : v2;
        float s = g[row] / sqrtf(v[row] + 1e-5f);
        (layer ? o3 : o2)[u] = (_Float16)(w[(row * 128 + c) * 3 + tap] * s);
    } else if (e < 123264) {                      // tvec: 3 x 128
        int i = e - 122880;
        int layer = i >> 7, ch = i & 127;
        const float* g = layer == 0 ? g1 : (layer == 1 ? g2 : g3);
        const float* b = layer == 0 ? b1 : (layer == 1 ? b2 : b3);
        const float* m = layer == 0 ? m1 : (layer == 1 ? m2 : m3);
        const float* v = layer == 0 ? v1 : (layer == 1 ? v2 : v3);
        float s = g[ch] / sqrtf(v[ch] + 1e-5f);
        tvec[i] = b[ch] - m[ch] * s;
    }
}

// ---------------------------------------------------------------------------
// Standalone gather: ONE thread per query, all 32 channels. No LDS, high
// occupancy -> gather latency hidden by TLP. Branchless batched corners
// (grid 7MB / sfeats 19MB are L2/L3-resident; ~8.5% cell occupancy so most
// corner loads collapse to the sfeats[0] broadcast with weight 0).
// Xg layout: [q][32] halves (interp channels only).
__global__ __launch_bounds__(256, 4) void k_interp(
    const float* __restrict__ pdh, const int* __restrict__ pts_batch,
    const float* __restrict__ sfeats, const int* __restrict__ grid,
    const int* __restrict__ minc, _Float16* __restrict__ Xg, int NQ, int n_sp)
{
    int gq = blockIdx.x * 256 + threadIdx.x;
    if (gq >= NQ) return;
    int pg = gq / 7;

    const float* pd = pdh + (size_t)gq * 3;
    float px = pd[0], py = pd[1], pz = pd[2];
    int b = pts_batch[pg];
    int mA0 = minc[0], mA1 = minc[1], mA2 = minc[2];
    int mB0 = minc[3], mB1 = minc[4], mB2 = minc[5];
    int m0 = b ? mB0 : mA0;
    int m1 = b ? mB1 : mA1;
    int m2 = b ? mB2 : mA2;
    float qx = (px - (float)m0 * RESV) / RESV;
    float qy = (py - (float)m1 * RESV) / RESV;
    float qz = (pz - (float)m2 * RESV) / RESV;
    float flx = floorf(qx), fly = floorf(qy), flz = floorf(qz);
    float fx = qx - flx, fy = qy - fly, fz = qz - flz;
    int ix0 = (int)flx, iy0 = (int)fly, iz0 = (int)flz;
    const int gbase = b * (GG * GG * GG);

    int   si[8];
    float wc[8];
#pragma unroll
    for (int c = 0; c < 8; ++c) {           // 8 grid loads, batched
        int dx = c >> 2, dy = (c >> 1) & 1, dz = c & 1;
        int cx = ix0 + dx, cy = iy0 + dy, cz = iz0 + dz;
        bool ok = ((unsigned)cx < GG) & ((unsigned)cy < GG) & ((unsigned)cz < GG);
        int cell = gbase + (cx * GG + cy) * GG + cz;
        wc[c] = ok ? (dx ? fx : 1.f - fx) * (dy ? fy : 1.f - fy)
                     * (dz ? fz : 1.f - fz)
                   : 0.f;
        si[c] = grid[ok ? cell : 0];
    }
    const f32x4* fb = (const f32x4*)sfeats;
    const f32x4* fpc[8];
    float w8[8];
#pragma unroll
    for (int c = 0; c < 8; ++c) {
        bool hit = si[c] < n_sp;            // empty cell = 0x7fffffff
        w8[c]  = hit ? wc[c] : 0.f;
        fpc[c] = fb + (size_t)(hit ? si[c] : 0) * 8;
    }
    float acc[32];
#pragma unroll
    for (int k2 = 0; k2 < 32; ++k2) acc[k2] = 0.f;
#pragma unroll
    for (int c = 0; c < 8; ++c) {           // 64 batched f32x4 loads total
        float w = w8[c];
#pragma unroll
        for (int v4 = 0; v4 < 8; ++v4) {
            f32x4 f = fpc[c][v4];
#pragma unroll
            for (int k2 = 0; k2 < 4; ++k2) acc[v4 * 4 + k2] += w * f[k2];
        }
    }
    f16x8 o[4];
#pragma unroll
    for (int v8 = 0; v8 < 4; ++v8)
#pragma unroll
        for (int k2 = 0; k2 < 8; ++k2) o[v8][k2] = (_Float16)acc[v8 * 8 + k2];
    _Float16* xp = Xg + (size_t)gq * 32;
#pragma unroll
    for (int v8 = 0; v8 < 4; ++v8) *(f16x8*)(xp + v8 * 8) = o[v8];
}

// ---------------------------------------------------------------------------
// One conv layer: D[128][128cols] = Wfold[128][3*CIN] * X_im2col + t, ReLU.
// Wave w: channel-half mp=w&1 (m-tiles 4mp..4mp+3), col-half (w>>1)*64.
// Per k-step: 4 A (global, prefetched PF=3 ahead) + 4 B (LDS, 1 ahead)
// -> 16 MFMA. 64ch x 64col register tile = 0.5 KB operand per MFMA.
template<int CIN, int KS>
__device__ __forceinline__ void conv_layer(
    const _Float16* xin, const _Float16* __restrict__ wg,
    const float* tvl, _Float16* hout, int tid)
{
    const int wave = tid >> 6;
    const int lane = tid & 63;
    const int quad = lane >> 4;
    const int l15  = lane & 15;
    const int mp   = wave & 1;
    const int cb   = (wave >> 1) * 64;

    constexpr int PF = 3;                 // A prefetch depth (covers ~220cy L2)
    f32x4 acc[4][4] = {};
    f16x8 Abuf[PF][4];
    f16x8 Bbuf[2][4];

    const _Float16* wbase = wg + (((size_t)(mp * 4) * KS) * 64 + lane) * 8;

    auto loadA = [&](int slot, int ks) {
#pragma unroll
        for (int m = 0; m < 4; ++m)
            Abuf[slot][m] = *(const f16x8*)(wbase + (size_t)(m * KS + ks) * 512);
    };
    auto loadB = [&](int slot, int ks) {
        const int k0   = ks * 32 + quad * 8;
        const int tap  = k0 / CIN;        // CIN 64/128 -> shifts
        const int c    = k0 & (CIN - 1);
        const int boff = (cb + l15 + tap) * CS + c;
#pragma unroll
        for (int ct = 0; ct < 4; ++ct)
            Bbuf[slot][ct] = *(const f16x8*)(xin + boff + ct * 16 * CS);
    };

#pragma unroll
    for (int p = 0; p < PF; ++p) loadA(p, p);
    loadB(0, 0);

#pragma unroll
    for (int ks = 0; ks < KS; ++ks) {
        if (ks + 1 < KS) loadB((ks + 1) & 1, ks + 1);
#pragma unroll
        for (int ct = 0; ct < 4; ++ct)
#pragma unroll
            for (int m = 0; m < 4; ++m)
                acc[ct][m] = __builtin_amdgcn_mfma_f32_16x16x32_f16(
                    Abuf[ks % PF][m], Bbuf[ks & 1][ct], acc[ct][m], 0, 0, 0);
        if (ks + PF < KS) loadA(ks % PF, ks + PF);   // refill just-consumed slot
    }

    // epilogue: +bias(t), ReLU, cvt fp16, store. D: col=lane&15, row=quad*4+i
    if ((l15 & 7) != 7) {                 // skip dead columns (keep zeros zero)
#pragma unroll
        for (int ct = 0; ct < 4; ++ct) {
            const int outc = cb + ct * 16 + l15;
            _Float16* dst = hout + (outc + 1) * CS + mp * 64 + quad * 4;
#pragma unroll
            for (int m = 0; m < 4; ++m) {
                const int ch = mp * 64 + m * 16 + quad * 4;
                f32x4 tval = *(const f32x4*)(tvl + ch);   // LDS broadcast
                f16x4 o;
#pragma unroll
                for (int i = 0; i < 4; ++i)
                    o[i] = (_Float16)fmaxf(acc[ct][m][i] + tval[i], 0.f);
                *(f16x4*)(dst + m * 16) = o;
            }
        }
    }
}

// ---------------------------------------------------------------------------
__global__ __launch_bounds__(256, 2) void k_main(
    const _Float16* __restrict__ Xg, const float* __restrict__ ptsfeat,
    const _Float16* __restrict__ w16_1, const _Float16* __restrict__ w16_2,
    const _Float16* __restrict__ w16_3, const float* __restrict__ tvec,
    const float* __restrict__ w4, const float* __restrict__ bias4,
    float* __restrict__ out, int N)
{
    __shared__ __align__(16) _Float16 hA[XC * CS];
    __shared__ __align__(16) _Float16 hB[XC * CS];
    __shared__ __align__(16) float    tv[384];
    __shared__ __align__(16) _Float16 w4h[384];

    const int tid = threadIdx.x;
    const int p0  = blockIdx.x * PT;

    // stage BN bias + w4 (im2col order k = tap*128 + c)
    for (int e = tid; e < 384; e += 256) {
        tv[e]  = tvec[e];
        w4h[e] = (_Float16)w4[(e & 127) * 3 + (e >> 7)];
    }
    // zero only the 18 dead/pad columns (u = 0,8,...,128 and 129), both buffers
    for (int idx = tid; idx < 18 * (CS / 2); idx += 256) {
        int cidx = idx / (CS / 2), off = idx % (CS / 2);
        int u = (cidx < 17) ? cidx * 8 : 129;
        ((int*)hA)[u * (CS / 2) + off] = 0;
        ((int*)hB)[u * (CS / 2) + off] = 0;
    }

    // ---- staging: Xg interp half (fp16) + ptsfeat direct (f32 NT, cvt)
    if (tid < 224) {
        int qi = tid >> 1, part = tid & 1;
        int pl = qi / 7, j = qi - pl * 7;
        int pg = p0 + pl;
        if (pg < N) {
            size_t gq = (size_t)pg * 7 + j;
            const f16x8* src = (const f16x8*)(Xg + gq * 32);
            f16x8 a = src[2 * part], b = src[2 * part + 1];
            const f32x4* pf = (const f32x4*)(ptsfeat + gq * 32 + part * 16);
            f32x4 pf0 = __builtin_nontemporal_load(pf + 0);
            f32x4 pf1 = __builtin_nontemporal_load(pf + 1);
            f32x4 pf2 = __builtin_nontemporal_load(pf + 2);
            f32x4 pf3 = __builtin_nontemporal_load(pf + 3);
            f16x8 p0v, p1v;
#pragma unroll
            for (int k2 = 0; k2 < 4; ++k2) {
                p0v[k2]     = (_Float16)pf0[k2];
                p0v[4 + k2] = (_Float16)pf1[k2];
                p1v[k2]     = (_Float16)pf2[k2];
                p1v[4 + k2] = (_Float16)pf3[k2];
            }
            _Float16* xp = hA + (pl * 8 + 1 + j) * CS;
            *(f16x8*)(xp + part * 16)          = a;
            *(f16x8*)(xp + part * 16 + 8)      = b;
            *(f16x8*)(xp + 32 + part * 16)     = p0v;
            *(f16x8*)(xp + 32 + part * 16 + 8) = p1v;
        }
    }
    __syncthreads();

    // ---- conv stack
    conv_layer<64,  6>(hA, w16_1, tv,       hB, tid);
    __syncthreads();
    conv_layer<128, 12>(hB, w16_2, tv + 128, hA, tid);
    __syncthreads();
    conv_layer<128, 12>(hA, w16_3, tv + 256, hB, tid);
    __syncthreads();

    // ---- layer 4 dot2 + in-wave shuffle softmax (point = 16 lanes, no LDS)
    {
        int col = tid >> 1, p4 = tid & 1;
        float sum = 0.f;
        if ((col & 7) != 7) {
#pragma unroll
            for (int t = 0; t < 3; ++t) {
                const _Float16* hp = hB + (col + t) * CS;
                const _Float16* wr = w4h + t * 128;
#pragma unroll
                for (int c8 = 0; c8 < 8; ++c8) {
                    int chunk = 2 * c8 + p4;          // bank-spread split
                    f16x8 h8 = *(const f16x8*)(hp + chunk * 8);
                    f16x8 w8 = *(const f16x8*)(wr + chunk * 8);
#pragma unroll
                    for (int p = 0; p < 4; ++p) {
                        f16x2 hv = { h8[2*p], h8[2*p+1] };
                        f16x2 wv = { w8[2*p], w8[2*p+1] };
#if __has_builtin(__builtin_amdgcn_fdot2)
                        sum = __builtin_amdgcn_fdot2(hv, wv, sum, false);
#else
                        sum += (float)hv[0]*(float)wv[0] + (float)hv[1]*(float)wv[1];
#endif
                    }
                }
            }
        }
        sum += __shfl_xor(sum, 1);                    // col total in both lanes
        float logit = sum + bias4[0];
        bool  dead  = (col & 7) == 7;
        float v = dead ? -1e30f : logit;
        v = fmaxf(v, __shfl_xor(v, 2));
        v = fmaxf(v, __shfl_xor(v, 4));
        v = fmaxf(v, __shfl_xor(v, 8));               // max over point's 7 cols
        float e = (!dead && p4 == 0) ? __expf(logit - v) : 0.f;
        float es = e;
        es += __shfl_xor(es, 2);
        es += __shfl_xor(es, 4);
        es += __shfl_xor(es, 8);                      // sum (even lanes valid)
        if (p4 == 0 && !dead) {
            int pgt = p0 + (col >> 3);
            if (pgt < N) out[(size_t)pgt * 7 + (col & 7)] = e / es;
        }
    }
}

// ---------------------------------------------------------------------------
extern "C" void kernel_launch(void* const* d_in, const int* in_sizes, int n_in,
                              void* d_out, int out_size, void* d_ws, size_t ws_size,
                              hipStream_t stream) {
    const int*   sparse_coords = (const int*)d_in[1];
    const int*   sparse_batch  = (const int*)d_in[2];
    const float* sparse_feats  = (const float*)d_in[3];
    const float* pdh           = (const float*)d_in[4];
    const float* ptsfeat       = (const float*)d_in[5];
    const int*   pts_batch     = (const int*)d_in[6];
    const float* w1 = (const float*)d_in[7];
    const float* g1 = (const float*)d_in[8],  *b1 = (const float*)d_in[9];
    const float* m1 = (const float*)d_in[10], *v1 = (const float*)d_in[11];
    const float* w2 = (const float*)d_in[12];
    const float* g2 = (const float*)d_in[13], *b2 = (const float*)d_in[14];
    const float* m2 = (const float*)d_in[15], *v2 = (const float*)d_in[16];
    const float* w3 = (const float*)d_in[17];
    const float* g3 = (const float*)d_in[18], *b3 = (const float*)d_in[19];
    const float* m3 = (const float*)d_in[20], *v3 = (const float*)d_in[21];
    const float* w4 = (const float*)d_in[22];
    const float* bias4 = (const float*)d_in[23];

    const int n_sp = in_sizes[2];
    const int N    = in_sizes[6];
    const int NQ   = N * 7;

    // workspace: [grid NG ints][minc 6][pad 16B][w16_1|w16_2|w16_3][tvec][Xg]
    int* grid = (int*)d_ws;
    int* minc = grid + NG;
    _Float16* w16_1 = (_Float16*)((char*)d_ws + (size_t)(NG + 6) * 4 + 8);
    _Float16* w16_2 = w16_1 + 128 * 192;
    _Float16* w16_3 = w16_2 + 128 * 384;
    float*    tvec  = (float*)(w16_3 + 128 * 384);
    _Float16* Xg    = (_Float16*)(tvec + 384);       // NQ*32 halves (~25.3MB)

    k_init<<<(NG / 4 + 255) / 256, 256, 0, stream>>>((int4*)grid, minc);
    k_scatter<<<(n_sp + 255) / 256, 256, 0, stream>>>(sparse_coords, sparse_batch,
                                                      n_sp, grid, minc);
    k_wconv<<<482, 256, 0, stream>>>(w1, w2, w3,
                                     g1, b1, m1, v1, g2, b2, m2, v2, g3, b3, m3, v3,
                                     w16_1, w16_2, w16_3, tvec);
    k_interp<<<(NQ + 255) / 256, 256, 0, stream>>>(
        pdh, pts_batch, sparse_feats, grid, minc, Xg, NQ, n_sp);
    k_main<<<(N + PT - 1) / PT, 256, 0, stream>>>(
        Xg, ptsfeat, w16_1, w16_2, w16_3, tvec, w4, bias4, (float*)d_out, N);
}

// Round 7
// 145.145 us; speedup vs baseline: 1.2732x; 1.2732x over previous
//
#include <hip/hip_runtime.h>

// ---------------------------------------------------------------------------
// HypothesisDecoder: dense-grid trilinear interp + fused fp16-MFMA conv stack
// Round 10: CONSOLIDATE. r8/r9 proved the kernel split is net-negative
// (k_interp standalone ~48us is NOT hidden; monolith hides most of the gather
// under the other resident block's conv). Base = r5b monolith (155us k_main,
// best verified): PT=16, 64x64 wave tiles, PF=3 weight prefetch, branchless
// batched gather inline. Two additive levers:
//  1) shuffle tail (proven in r8's k_main): layer-4 dot2 + in-wave softmax,
//     no lg LDS, one fewer barrier.
//  2) s_setprio(1) around the MFMA cluster (T5): CU runs 2 independent
//     blocks at anti-correlated phases (staging VMEM vs conv MFMA) -- role
//     diversity is present, so priority arbitration should favor the conv
//     wave without hurting the latency-bound staging block.
// ---------------------------------------------------------------------------
#define GG 96
#define NB 2
#define RESV 0.04f

constexpr int NG  = NB * GG * GG * GG;  // dense voxel grid cells (1,769,472)
constexpr int PT  = 16;                 // points per block
constexpr int NCOLS = PT * 8;           // 128 output columns (7 real + 1 dead per pt)
constexpr int XC  = NCOLS + 2;          // 130 LDS columns
constexpr int CS  = 136;                // LDS stride in halves (272B = 68 dwords)

typedef _Float16 f16x8 __attribute__((ext_vector_type(8)));
typedef _Float16 f16x4 __attribute__((ext_vector_type(4)));
typedef _Float16 f16x2 __attribute__((ext_vector_type(2)));
typedef float    f32x4 __attribute__((ext_vector_type(4)));

// ---------------------------------------------------------------------------
__global__ void k_init(int4* __restrict__ grid4, int* __restrict__ minc) {
    int i = blockIdx.x * 256 + threadIdx.x;
    if (i < NG / 4) grid4[i] = make_int4(0x7fffffff, 0x7fffffff, 0x7fffffff, 0x7fffffff);
    if (i < 6)      minc[i] = 0x7fffffff;
}

__global__ void k_scatter(const int* __restrict__ coords, const int* __restrict__ sbatch,
                          int n, int* __restrict__ grid, int* __restrict__ minc) {
    __shared__ int lmin[6];
    int tid = threadIdx.x;
    if (tid < 6) lmin[tid] = 0x7fffffff;
    __syncthreads();
    int i = blockIdx.x * 256 + tid;
    if (i < n) {
        int cx = coords[3*i], cy = coords[3*i+1], cz = coords[3*i+2];
        int b = sbatch[i];
        // stable-argsort + leftmost searchsorted == keep smallest original index
        atomicMin(&grid[((b*GG + cx)*GG + cy)*GG + cz], i);
        atomicMin(&lmin[b*3+0], cx);
        atomicMin(&lmin[b*3+1], cy);
        atomicMin(&lmin[b*3+2], cz);
    }
    __syncthreads();
    if (tid < 6) atomicMin(&minc[tid], lmin[tid]);
}

// ---------------------------------------------------------------------------
// Weights -> fp16 MFMA-fragment order with BN scale folded in.
// Fragment index: (((mt*KS + ks)*64 + lane)*8 + j) ; element:
//   row = mt*16 + (lane&15), k = ks*32 + (lane>>4)*8 + j, tap = k/CIN, c = k%CIN
// tvec[layer*128 + ch] = b - m * (g / sqrt(v + eps))
__global__ void k_wconv(const float* __restrict__ w1, const float* __restrict__ w2,
                        const float* __restrict__ w3,
                        const float* __restrict__ g1, const float* __restrict__ b1,
                        const float* __restrict__ m1, const float* __restrict__ v1,
                        const float* __restrict__ g2, const float* __restrict__ b2,
                        const float* __restrict__ m2, const float* __restrict__ v2,
                        const float* __restrict__ g3, const float* __restrict__ b3,
                        const float* __restrict__ m3, const float* __restrict__ v3,
                        _Float16* __restrict__ o1, _Float16* __restrict__ o2,
                        _Float16* __restrict__ o3, float* __restrict__ tvec) {
    int e = blockIdx.x * 256 + threadIdx.x;
    if (e < 24576) {                              // layer 1: 128 x 192, KS=6
        int j = e & 7, lane = (e >> 3) & 63, t2 = e >> 9;   // t2 in [0,48)
        int mt = t2 / 6, ks = t2 % 6;
        int row = mt * 16 + (lane & 15);
        int k = ks * 32 + ((lane >> 4) << 3) + j;
        int tap = k >> 6, c = k & 63;
        float s = g1[row] / sqrtf(v1[row] + 1e-5f);
        o1[e] = (_Float16)(w1[(row * 64 + c) * 3 + tap] * s);
    } else if (e < 122880) {                      // layers 2/3: 128 x 384, KS=12
        int u = e - 24576;
        int layer = u / 49152;
        u %= 49152;
        int j = u & 7, lane = (u >> 3) & 63, t2 = u >> 9;   // t2 in [0,96)
        int mt = t2 / 12, ks = t2 % 12;
        int row = mt * 16 + (lane & 15);
        int k = ks * 32 + ((lane >> 4) << 3) + j;
        int tap = k >> 7, c = k & 127;
        const float* w = layer ? w3 : w2;
        const float* g = layer ? g3 : g2;
        const float* v = layer ? v3 : v2;
        float s = g[row] / sqrtf(v[row] + 1e-5f);
        (layer ? o3 : o2)[u] = (_Float16)(w[(row * 128 + c) * 3 + tap] * s);
    } else if (e < 123264) {                      // tvec: 3 x 128
        int i = e - 122880;
        int layer = i >> 7, ch = i & 127;
        const float* g = layer == 0 ? g1 : (layer == 1 ? g2 : g3);
        const float* b = layer == 0 ? b1 : (layer == 1 ? b2 : b3);
        const float* m = layer == 0 ? m1 : (layer == 1 ? m2 : m3);
        const float* v = layer == 0 ? v1 : (layer == 1 ? v2 : v3);
        float s = g[ch] / sqrtf(v[ch] + 1e-5f);
        tvec[i] = b[ch] - m[ch] * s;
    }
}

// ---------------------------------------------------------------------------
// One conv layer: D[128][128cols] = Wfold[128][3*CIN] * X_im2col + t, ReLU.
// Wave w: channel-half mp=w&1 (m-tiles 4mp..4mp+3), col-half (w>>1)*64.
// Per k-step: 4 A (global, prefetched PF=3 ahead) + 4 B (LDS, 1 ahead)
// -> 16 MFMA wrapped in setprio(1) (T5: 2 blocks/CU at different phases).
template<int CIN, int KS>
__device__ __forceinline__ void conv_layer(
    const _Float16* xin, const _Float16* __restrict__ wg,
    const float* tvl, _Float16* hout, int tid)
{
    const int wave = tid >> 6;
    const int lane = tid & 63;
    const int quad = lane >> 4;
    const int l15  = lane & 15;
    const int mp   = wave & 1;
    const int cb   = (wave >> 1) * 64;

    constexpr int PF = 3;                 // A prefetch depth (covers ~220cy L2)
    f32x4 acc[4][4] = {};
    f16x8 Abuf[PF][4];
    f16x8 Bbuf[2][4];

    const _Float16* wbase = wg + (((size_t)(mp * 4) * KS) * 64 + lane) * 8;

    auto loadA = [&](int slot, int ks) {
#pragma unroll
        for (int m = 0; m < 4; ++m)
            Abuf[slot][m] = *(const f16x8*)(wbase + (size_t)(m * KS + ks) * 512);
    };
    auto loadB = [&](int slot, int ks) {
        const int k0   = ks * 32 + quad * 8;
        const int tap  = k0 / CIN;        // CIN 64/128 -> shifts
        const int c    = k0 & (CIN - 1);
        const int boff = (cb + l15 + tap) * CS + c;
#pragma unroll
        for (int ct = 0; ct < 4; ++ct)
            Bbuf[slot][ct] = *(const f16x8*)(xin + boff + ct * 16 * CS);
    };

#pragma unroll
    for (int p = 0; p < PF; ++p) loadA(p, p);
    loadB(0, 0);

#pragma unroll
    for (int ks = 0; ks < KS; ++ks) {
        if (ks + 1 < KS) loadB((ks + 1) & 1, ks + 1);
        __builtin_amdgcn_s_setprio(1);
#pragma unroll
        for (int ct = 0; ct < 4; ++ct)
#pragma unroll
            for (int m = 0; m < 4; ++m)
                acc[ct][m] = __builtin_amdgcn_mfma_f32_16x16x32_f16(
                    Abuf[ks % PF][m], Bbuf[ks & 1][ct], acc[ct][m], 0, 0, 0);
        __builtin_amdgcn_s_setprio(0);
        if (ks + PF < KS) loadA(ks % PF, ks + PF);   // refill just-consumed slot
    }

    // epilogue: +bias(t), ReLU, cvt fp16, store. D: col=lane&15, row=quad*4+i
    if ((l15 & 7) != 7) {                 // skip dead columns (keep zeros zero)
#pragma unroll
        for (int ct = 0; ct < 4; ++ct) {
            const int outc = cb + ct * 16 + l15;
            _Float16* dst = hout + (outc + 1) * CS + mp * 64 + quad * 4;
#pragma unroll
            for (int m = 0; m < 4; ++m) {
                const int ch = mp * 64 + m * 16 + quad * 4;
                f32x4 tval = *(const f32x4*)(tvl + ch);   // LDS broadcast
                f16x4 o;
#pragma unroll
                for (int i = 0; i < 4; ++i)
                    o[i] = (_Float16)fmaxf(acc[ct][m][i] + tval[i], 0.f);
                *(f16x4*)(dst + m * 16) = o;
            }
        }
    }
}

// ---------------------------------------------------------------------------
__global__ __launch_bounds__(256, 2) void k_main(
    const float* __restrict__ pdh, const float* __restrict__ ptsfeat,
    const int* __restrict__ pts_batch, const float* __restrict__ sfeats,
    const int* __restrict__ grid, const int* __restrict__ minc,
    const _Float16* __restrict__ w16_1, const _Float16* __restrict__ w16_2,
    const _Float16* __restrict__ w16_3, const float* __restrict__ tvec,
    const float* __restrict__ w4, const float* __restrict__ bias4,
    float* __restrict__ out, int N, int n_sp)
{
    __shared__ __align__(16) _Float16 hA[XC * CS];
    __shared__ __align__(16) _Float16 hB[XC * CS];
    __shared__ __align__(16) float    tv[384];
    __shared__ __align__(16) _Float16 w4h[384];

    const int tid = threadIdx.x;
    const int p0  = blockIdx.x * PT;

    // stage BN bias + w4 (im2col order k = tap*128 + c)
    for (int e = tid; e < 384; e += 256) {
        tv[e]  = tvec[e];
        w4h[e] = (_Float16)w4[(e & 127) * 3 + (e >> 7)];
    }
    // zero only the 18 dead/pad columns (u = 0,8,...,128 and 129), both buffers
    for (int idx = tid; idx < 18 * (CS / 2); idx += 256) {
        int cidx = idx / (CS / 2), off = idx % (CS / 2);
        int u = (cidx < 17) ? cidx * 8 : 129;
        ((int*)hA)[u * (CS / 2) + off] = 0;
        ((int*)hB)[u * (CS / 2) + off] = 0;
    }

    // ---- trilinear interp + pts_feat staging: 112 queries x 2 ch-parts.
    // Branchless batched gather: 1 latency round for 8 grid loads, 1 for the
    // 8x64B feature loads (misses -> sfeats[0] broadcast with weight 0).
    if (tid < 224) {
        int q = tid >> 1, part = tid & 1;
        int pl = q / 7, j = q - pl * 7;
        int pg = p0 + pl;
        if (pg < N) {
            // early-issue the read-once HBM streams (non-temporal: keep L2
            // for grid/sfeats/weights); latency hides under the gather chain
            const f32x4* pf = (const f32x4*)(ptsfeat + ((size_t)pg * 7 + j) * 32 + part * 16);
            f32x4 pf0 = __builtin_nontemporal_load(pf + 0);
            f32x4 pf1 = __builtin_nontemporal_load(pf + 1);
            f32x4 pf2 = __builtin_nontemporal_load(pf + 2);
            f32x4 pf3 = __builtin_nontemporal_load(pf + 3);
            const float* pd = pdh + ((size_t)pg * 7 + j) * 3;
            float px = pd[0], py = pd[1], pz = pd[2];
            // minc: load all 6 in parallel with pts_batch, select by b after
            int b = pts_batch[pg];
            int mA0 = minc[0], mA1 = minc[1], mA2 = minc[2];
            int mB0 = minc[3], mB1 = minc[4], mB2 = minc[5];
            int m0 = b ? mB0 : mA0;
            int m1 = b ? mB1 : mA1;
            int m2 = b ? mB2 : mA2;
            float qx = (px - (float)m0 * RESV) / RESV;
            float qy = (py - (float)m1 * RESV) / RESV;
            float qz = (pz - (float)m2 * RESV) / RESV;
            float flx = floorf(qx), fly = floorf(qy), flz = floorf(qz);
            float fx = qx - flx, fy = qy - fly, fz = qz - flz;
            int ix0 = (int)flx, iy0 = (int)fly, iz0 = (int)flz;
            const int gbase = b * (GG * GG * GG);

            int   si[8];
            float wc[8];
#pragma unroll
            for (int c = 0; c < 8; ++c) {           // 8 grid loads, batched
                int dx = c >> 2, dy = (c >> 1) & 1, dz = c & 1;
                int cx = ix0 + dx, cy = iy0 + dy, cz = iz0 + dz;
                bool ok = ((unsigned)cx < GG) & ((unsigned)cy < GG) & ((unsigned)cz < GG);
                int cell = gbase + (cx * GG + cy) * GG + cz;
                wc[c] = ok ? (dx ? fx : 1.f - fx) * (dy ? fy : 1.f - fy)
                             * (dz ? fz : 1.f - fz)
                           : 0.f;
                si[c] = grid[ok ? cell : 0];
            }
            const f32x4* fb = (const f32x4*)sfeats;
            const f32x4* fpc[8];
            float w8[8];
#pragma unroll
            for (int c = 0; c < 8; ++c) {
                bool hit = si[c] < n_sp;            // empty cell = 0x7fffffff
                w8[c]  = hit ? wc[c] : 0.f;
                fpc[c] = fb + (size_t)(hit ? si[c] : 0) * 8 + part * 4;
            }
            float acc[16];
#pragma unroll
            for (int k2 = 0; k2 < 16; ++k2) acc[k2] = 0.f;
#pragma unroll
            for (int c = 0; c < 8; ++c) {           // 32 f32x4 loads, batched
                f32x4 f0 = fpc[c][0], f1 = fpc[c][1], f2 = fpc[c][2], f3 = fpc[c][3];
                float w = w8[c];
#pragma unroll
                for (int k2 = 0; k2 < 4; ++k2) {
                    acc[k2]      += w * f0[k2];
                    acc[4 + k2]  += w * f1[k2];
                    acc[8 + k2]  += w * f2[k2];
                    acc[12 + k2] += w * f3[k2];
                }
            }
            int u = pl * 8 + 1 + j;
            _Float16* xp = hA + u * CS + part * 16;
            f16x8 h0, h1;
#pragma unroll
            for (int k2 = 0; k2 < 8; ++k2) { h0[k2] = (_Float16)acc[k2]; h1[k2] = (_Float16)acc[8 + k2]; }
            *(f16x8*)xp = h0;
            *(f16x8*)(xp + 8) = h1;
            f16x8 p0v, p1v;
#pragma unroll
            for (int k2 = 0; k2 < 4; ++k2) {
                p0v[k2]     = (_Float16)pf0[k2];
                p0v[4 + k2] = (_Float16)pf1[k2];
                p1v[k2]     = (_Float16)pf2[k2];
                p1v[4 + k2] = (_Float16)pf3[k2];
            }
            *(f16x8*)(hA + u * CS + 32 + part * 16) = p0v;
            *(f16x8*)(hA + u * CS + 40 + part * 16) = p1v;
        }
    }
    __syncthreads();

    // ---- conv stack
    conv_layer<64,  6>(hA, w16_1, tv,       hB, tid);
    __syncthreads();
    conv_layer<128, 12>(hB, w16_2, tv + 128, hA, tid);
    __syncthreads();
    conv_layer<128, 12>(hA, w16_3, tv + 256, hB, tid);
    __syncthreads();

    // ---- layer 4 dot2 + in-wave shuffle softmax (point = 16 lanes, no LDS)
    {
        int col = tid >> 1, p4 = tid & 1;
        float sum = 0.f;
        if ((col & 7) != 7) {
#pragma unroll
            for (int t = 0; t < 3; ++t) {
                const _Float16* hp = hB + (col + t) * CS;
                const _Float16* wr = w4h + t * 128;
#pragma unroll
                for (int c8 = 0; c8 < 8; ++c8) {
                    int chunk = 2 * c8 + p4;          // bank-spread split
                    f16x8 h8 = *(const f16x8*)(hp + chunk * 8);
                    f16x8 w8 = *(const f16x8*)(wr + chunk * 8);
#pragma unroll
                    for (int p = 0; p < 4; ++p) {
                        f16x2 hv = { h8[2*p], h8[2*p+1] };
                        f16x2 wv = { w8[2*p], w8[2*p+1] };
#if __has_builtin(__builtin_amdgcn_fdot2)
                        sum = __builtin_amdgcn_fdot2(hv, wv, sum, false);
#else
                        sum += (float)hv[0]*(float)wv[0] + (float)hv[1]*(float)wv[1];
#endif
                    }
                }
            }
        }
        sum += __shfl_xor(sum, 1);                    // col total in both lanes
        float logit = sum + bias4[0];
        bool  dead  = (col & 7) == 7;
        float v = dead ? -1e30f : logit;
        v = fmaxf(v, __shfl_xor(v, 2));
        v = fmaxf(v, __shfl_xor(v, 4));
        v = fmaxf(v, __shfl_xor(v, 8));               // max over point's 7 cols
        float e = (!dead && p4 == 0) ? __expf(logit - v) : 0.f;
        float es = e;
        es += __shfl_xor(es, 2);
        es += __shfl_xor(es, 4);
        es += __shfl_xor(es, 8);                      // sum (even lanes valid)
        if (p4 == 0 && !dead) {
            int pgt = p0 + (col >> 3);
            if (pgt < N) out[(size_t)pgt * 7 + (col & 7)] = e / es;
        }
    }
}

// ---------------------------------------------------------------------------
extern "C" void kernel_launch(void* const* d_in, const int* in_sizes, int n_in,
                              void* d_out, int out_size, void* d_ws, size_t ws_size,
                              hipStream_t stream) {
    const int*   sparse_coords = (const int*)d_in[1];
    const int*   sparse_batch  = (const int*)d_in[2];
    const float* sparse_feats  = (const float*)d_in[3];
    const float* pdh           = (const float*)d_in[4];
    const float* ptsfeat       = (const float*)d_in[5];
    const int*   pts_batch     = (const int*)d_in[6];
    const float* w1 = (const float*)d_in[7];
    const float* g1 = (const float*)d_in[8],  *b1 = (const float*)d_in[9];
    const float* m1 = (const float*)d_in[10], *v1 = (const float*)d_in[11];
    const float* w2 = (const float*)d_in[12];
    const float* g2 = (const float*)d_in[13], *b2 = (const float*)d_in[14];
    const float* m2 = (const float*)d_in[15], *v2 = (const float*)d_in[16];
    const float* w3 = (const float*)d_in[17];
    const float* g3 = (const float*)d_in[18], *b3 = (const float*)d_in[19];
    const float* m3 = (const float*)d_in[20], *v3 = (const float*)d_in[21];
    const float* w4 = (const float*)d_in[22];
    const float* bias4 = (const float*)d_in[23];

    const int n_sp = in_sizes[2];
    const int N    = in_sizes[6];

    // workspace: [grid NG ints][minc 6][pad to 16B][w16_1|w16_2|w16_3][tvec]
    int* grid = (int*)d_ws;
    int* minc = grid + NG;
    _Float16* w16_1 = (_Float16*)((char*)d_ws + (size_t)(NG + 6) * 4 + 8);
    _Float16* w16_2 = w16_1 + 128 * 192;
    _Float16* w16_3 = w16_2 + 128 * 384;
    float*    tvec  = (float*)(w16_3 + 128 * 384);

    k_init<<<(NG / 4 + 255) / 256, 256, 0, stream>>>((int4*)grid, minc);
    k_scatter<<<(n_sp + 255) / 256, 256, 0, stream>>>(sparse_coords, sparse_batch,
                                                      n_sp, grid, minc);
    k_wconv<<<482, 256, 0, stream>>>(w1, w2, w3,
                                     g1, b1, m1, v1, g2, b2, m2, v2, g3, b3, m3, v3,
                                     w16_1, w16_2, w16_3, tvec);
    k_main<<<(N + PT - 1) / PT, 256, 0, stream>>>(
        pdh, ptsfeat, pts_batch, sparse_feats, grid, minc,
        w16_1, w16_2, w16_3, tvec, w4, bias4, (float*)d_out, N, n_sp);
}

// Round 8
// 142.759 us; speedup vs baseline: 1.2944x; 1.0167x over previous
//
#include <hip/hip_runtime.h>

// ---------------------------------------------------------------------------
// HypothesisDecoder: dense-grid trilinear interp + fused fp16-MFMA conv stack
// Round 11: r10 (145us: monolith + shuffle tail + setprio) + epilogue VALU
// cuts. VALUBusy 29% breakdown: conv epilogues ~53Kcy/CU (largest item,
// inside the barrier-bounded conv region). Changes:
//  1) BN bias folded into acc INIT (MFMA C-in does the add for free);
//     also kills the 16 per-thread tvl LDS reads per epilogue.
//  2) ReLU after cvt as packed f16 max (v_pk_max_f16 via
//     __builtin_elementwise_max): 64 scalar fmax -> 16 packed.
//  3) staging global loads (ptsfeat/pdh/batch) issued BEFORE the prologue
//     zero-fill so first-touch latency hides under independent work.
// ---------------------------------------------------------------------------
#define GG 96
#define NB 2
#define RESV 0.04f

constexpr int NG  = NB * GG * GG * GG;  // dense voxel grid cells (1,769,472)
constexpr int PT  = 16;                 // points per block
constexpr int NCOLS = PT * 8;           // 128 output columns (7 real + 1 dead per pt)
constexpr int XC  = NCOLS + 2;          // 130 LDS columns
constexpr int CS  = 136;                // LDS stride in halves (272B = 68 dwords)

typedef _Float16 f16x8 __attribute__((ext_vector_type(8)));
typedef _Float16 f16x4 __attribute__((ext_vector_type(4)));
typedef _Float16 f16x2 __attribute__((ext_vector_type(2)));
typedef float    f32x4 __attribute__((ext_vector_type(4)));

// ---------------------------------------------------------------------------
__global__ void k_init(int4* __restrict__ grid4, int* __restrict__ minc) {
    int i = blockIdx.x * 256 + threadIdx.x;
    if (i < NG / 4) grid4[i] = make_int4(0x7fffffff, 0x7fffffff, 0x7fffffff, 0x7fffffff);
    if (i < 6)      minc[i] = 0x7fffffff;
}

__global__ void k_scatter(const int* __restrict__ coords, const int* __restrict__ sbatch,
                          int n, int* __restrict__ grid, int* __restrict__ minc) {
    __shared__ int lmin[6];
    int tid = threadIdx.x;
    if (tid < 6) lmin[tid] = 0x7fffffff;
    __syncthreads();
    int i = blockIdx.x * 256 + tid;
    if (i < n) {
        int cx = coords[3*i], cy = coords[3*i+1], cz = coords[3*i+2];
        int b = sbatch[i];
        // stable-argsort + leftmost searchsorted == keep smallest original index
        atomicMin(&grid[((b*GG + cx)*GG + cy)*GG + cz], i);
        atomicMin(&lmin[b*3+0], cx);
        atomicMin(&lmin[b*3+1], cy);
        atomicMin(&lmin[b*3+2], cz);
    }
    __syncthreads();
    if (tid < 6) atomicMin(&minc[tid], lmin[tid]);
}

// ---------------------------------------------------------------------------
// Weights -> fp16 MFMA-fragment order with BN scale folded in.
// Fragment index: (((mt*KS + ks)*64 + lane)*8 + j) ; element:
//   row = mt*16 + (lane&15), k = ks*32 + (lane>>4)*8 + j, tap = k/CIN, c = k%CIN
// tvec[layer*128 + ch] = b - m * (g / sqrt(v + eps))
__global__ void k_wconv(const float* __restrict__ w1, const float* __restrict__ w2,
                        const float* __restrict__ w3,
                        const float* __restrict__ g1, const float* __restrict__ b1,
                        const float* __restrict__ m1, const float* __restrict__ v1,
                        const float* __restrict__ g2, const float* __restrict__ b2,
                        const float* __restrict__ m2, const float* __restrict__ v2,
                        const float* __restrict__ g3, const float* __restrict__ b3,
                        const float* __restrict__ m3, const float* __restrict__ v3,
                        _Float16* __restrict__ o1, _Float16* __restrict__ o2,
                        _Float16* __restrict__ o3, float* __restrict__ tvec) {
    int e = blockIdx.x * 256 + threadIdx.x;
    if (e < 24576) {                              // layer 1: 128 x 192, KS=6
        int j = e & 7, lane = (e >> 3) & 63, t2 = e >> 9;   // t2 in [0,48)
        int mt = t2 / 6, ks = t2 % 6;
        int row = mt * 16 + (lane & 15);
        int k = ks * 32 + ((lane >> 4) << 3) + j;
        int tap = k >> 6, c = k & 63;
        float s = g1[row] / sqrtf(v1[row] + 1e-5f);
        o1[e] = (_Float16)(w1[(row * 64 + c) * 3 + tap] * s);
    } else if (e < 122880) {                      // layers 2/3: 128 x 384, KS=12
        int u = e - 24576;
        int layer = u / 49152;
        u %= 49152;
        int j = u & 7, lane = (u >> 3) & 63, t2 = u >> 9;   // t2 in [0,96)
        int mt = t2 / 12, ks = t2 % 12;
        int row = mt * 16 + (lane & 15);
        int k = ks * 32 + ((lane >> 4) << 3) + j;
        int tap = k >> 7, c = k & 127;
        const float* w = layer ? w3 : w2;
        const float* g = layer ? g3 : g2;
        const float* v = layer ? v3 : v2;
        float s = g[row] / sqrtf(v[row] + 1e-5f);
        (layer ? o3 : o2)[u] = (_Float16)(w[(row * 128 + c) * 3 + tap] * s);
    } else if (e < 123264) {                      // tvec: 3 x 128
        int i = e - 122880;
        int layer = i >> 7, ch = i & 127;
        const float* g = layer == 0 ? g1 : (layer == 1 ? g2 : g3);
        const float* b = layer == 0 ? b1 : (layer == 1 ? b2 : b3);
        const float* m = layer == 0 ? m1 : (layer == 1 ? m2 : m3);
        const float* v = layer == 0 ? v1 : (layer == 1 ? v2 : v3);
        float s = g[ch] / sqrtf(v[ch] + 1e-5f);
        tvec[i] = b[ch] - m[ch] * s;
    }
}

// ---------------------------------------------------------------------------
// One conv layer: D[128][128cols] = Wfold[128][3*CIN] * X_im2col + t, ReLU.
// Wave w: channel-half mp=w&1 (m-tiles 4mp..4mp+3), col-half (w>>1)*64.
// Per k-step: 4 A (global, prefetched PF=3 ahead) + 4 B (LDS, 1 ahead)
// -> 16 MFMA wrapped in setprio(1) (T5). Bias t pre-loaded into acc (MFMA
// C-in does the add); epilogue = cvt + packed f16 ReLU + store only.
template<int CIN, int KS>
__device__ __forceinline__ void conv_layer(
    const _Float16* xin, const _Float16* __restrict__ wg,
    const float* tvl, _Float16* hout, int tid)
{
    const int wave = tid >> 6;
    const int lane = tid & 63;
    const int quad = lane >> 4;
    const int l15  = lane & 15;
    const int mp   = wave & 1;
    const int cb   = (wave >> 1) * 64;

    constexpr int PF = 3;                 // A prefetch depth (covers ~220cy L2)
    f16x8 Abuf[PF][4];
    f16x8 Bbuf[2][4];

    // acc init = BN bias (broadcast LDS read, 4 x b128; same addr per quad)
    f32x4 tval4[4];
#pragma unroll
    for (int m = 0; m < 4; ++m)
        tval4[m] = *(const f32x4*)(tvl + mp * 64 + m * 16 + quad * 4);
    f32x4 acc[4][4];
#pragma unroll
    for (int ct = 0; ct < 4; ++ct)
#pragma unroll
        for (int m = 0; m < 4; ++m) acc[ct][m] = tval4[m];

    const _Float16* wbase = wg + (((size_t)(mp * 4) * KS) * 64 + lane) * 8;

    auto loadA = [&](int slot, int ks) {
#pragma unroll
        for (int m = 0; m < 4; ++m)
            Abuf[slot][m] = *(const f16x8*)(wbase + (size_t)(m * KS + ks) * 512);
    };
    auto loadB = [&](int slot, int ks) {
        const int k0   = ks * 32 + quad * 8;
        const int tap  = k0 / CIN;        // CIN 64/128 -> shifts
        const int c    = k0 & (CIN - 1);
        const int boff = (cb + l15 + tap) * CS + c;
#pragma unroll
        for (int ct = 0; ct < 4; ++ct)
            Bbuf[slot][ct] = *(const f16x8*)(xin + boff + ct * 16 * CS);
    };

#pragma unroll
    for (int p = 0; p < PF; ++p) loadA(p, p);
    loadB(0, 0);

#pragma unroll
    for (int ks = 0; ks < KS; ++ks) {
        if (ks + 1 < KS) loadB((ks + 1) & 1, ks + 1);
        __builtin_amdgcn_s_setprio(1);
#pragma unroll
        for (int ct = 0; ct < 4; ++ct)
#pragma unroll
            for (int m = 0; m < 4; ++m)
                acc[ct][m] = __builtin_amdgcn_mfma_f32_16x16x32_f16(
                    Abuf[ks % PF][m], Bbuf[ks & 1][ct], acc[ct][m], 0, 0, 0);
        __builtin_amdgcn_s_setprio(0);
        if (ks + PF < KS) loadA(ks % PF, ks + PF);   // refill just-consumed slot
    }

    // epilogue: cvt fp16, packed ReLU, store. D: col=lane&15, row=quad*4+i
    // (relu commutes with cvt: monotone, 0->0)
    if ((l15 & 7) != 7) {                 // skip dead columns (keep zeros zero)
        const f16x4 zero4 = {(_Float16)0.f, (_Float16)0.f, (_Float16)0.f, (_Float16)0.f};
#pragma unroll
        for (int ct = 0; ct < 4; ++ct) {
            const int outc = cb + ct * 16 + l15;
            _Float16* dst = hout + (outc + 1) * CS + mp * 64 + quad * 4;
#pragma unroll
            for (int m = 0; m < 4; ++m) {
                f16x4 o;
#pragma unroll
                for (int i = 0; i < 4; ++i)
                    o[i] = (_Float16)acc[ct][m][i];
#if __has_builtin(__builtin_elementwise_max)
                o = __builtin_elementwise_max(o, zero4);   // v_pk_max_f16 x2
#else
#pragma unroll
                for (int i = 0; i < 4; ++i)
                    o[i] = o[i] > (_Float16)0.f ? o[i] : (_Float16)0.f;
#endif
                *(f16x4*)(dst + m * 16) = o;
            }
        }
    }
}

// ---------------------------------------------------------------------------
__global__ __launch_bounds__(256, 2) void k_main(
    const float* __restrict__ pdh, const float* __restrict__ ptsfeat,
    const int* __restrict__ pts_batch, const float* __restrict__ sfeats,
    const int* __restrict__ grid, const int* __restrict__ minc,
    const _Float16* __restrict__ w16_1, const _Float16* __restrict__ w16_2,
    const _Float16* __restrict__ w16_3, const float* __restrict__ tvec,
    const float* __restrict__ w4, const float* __restrict__ bias4,
    float* __restrict__ out, int N, int n_sp)
{
    __shared__ __align__(16) _Float16 hA[XC * CS];
    __shared__ __align__(16) _Float16 hB[XC * CS];
    __shared__ __align__(16) float    tv[384];
    __shared__ __align__(16) _Float16 w4h[384];

    const int tid = threadIdx.x;
    const int p0  = blockIdx.x * PT;

    // ---- interp roles; issue the read-once global streams FIRST so their
    // first-touch latency hides under the prologue staging/zero-fill below
    const int q = tid >> 1, part = tid & 1;
    const int pl = q / 7, j = q - pl * 7;
    const int pg = p0 + pl;
    const bool act = (tid < 224) && (pg < N);
    f32x4 pf0 = {}, pf1 = {}, pf2 = {}, pf3 = {};
    float px = 0.f, py = 0.f, pz = 0.f;
    int b = 0;
    if (act) {
        const f32x4* pf = (const f32x4*)(ptsfeat + ((size_t)pg * 7 + j) * 32 + part * 16);
        pf0 = __builtin_nontemporal_load(pf + 0);
        pf1 = __builtin_nontemporal_load(pf + 1);
        pf2 = __builtin_nontemporal_load(pf + 2);
        pf3 = __builtin_nontemporal_load(pf + 3);
        const float* pd = pdh + ((size_t)pg * 7 + j) * 3;
        px = pd[0]; py = pd[1]; pz = pd[2];
        b = pts_batch[pg];
    }
    const int mA0 = minc[0], mA1 = minc[1], mA2 = minc[2];   // uniform scalar
    const int mB0 = minc[3], mB1 = minc[4], mB2 = minc[5];

    // stage BN bias + w4 (im2col order k = tap*128 + c)
    for (int e = tid; e < 384; e += 256) {
        tv[e]  = tvec[e];
        w4h[e] = (_Float16)w4[(e & 127) * 3 + (e >> 7)];
    }
    // zero only the 18 dead/pad columns (u = 0,8,...,128 and 129), both buffers
    for (int idx = tid; idx < 18 * (CS / 2); idx += 256) {
        int cidx = idx / (CS / 2), off = idx % (CS / 2);
        int u = (cidx < 17) ? cidx * 8 : 129;
        ((int*)hA)[u * (CS / 2) + off] = 0;
        ((int*)hB)[u * (CS / 2) + off] = 0;
    }

    // ---- trilinear interp: branchless batched gather (1 latency round for
    // 8 grid loads, 1 for the 8x64B feature loads; miss -> sfeats[0], w=0)
    if (act) {
        int m0 = b ? mB0 : mA0;
        int m1 = b ? mB1 : mA1;
        int m2 = b ? mB2 : mA2;
        float qx = (px - (float)m0 * RESV) / RESV;
        float qy = (py - (float)m1 * RESV) / RESV;
        float qz = (pz - (float)m2 * RESV) / RESV;
        float flx = floorf(qx), fly = floorf(qy), flz = floorf(qz);
        float fx = qx - flx, fy = qy - fly, fz = qz - flz;
        int ix0 = (int)flx, iy0 = (int)fly, iz0 = (int)flz;
        const int gbase = b * (GG * GG * GG);

        int   si[8];
        float wc[8];
#pragma unroll
        for (int c = 0; c < 8; ++c) {           // 8 grid loads, batched
            int dx = c >> 2, dy = (c >> 1) & 1, dz = c & 1;
            int cx = ix0 + dx, cy = iy0 + dy, cz = iz0 + dz;
            bool ok = ((unsigned)cx < GG) & ((unsigned)cy < GG) & ((unsigned)cz < GG);
            int cell = gbase + (cx * GG + cy) * GG + cz;
            wc[c] = ok ? (dx ? fx : 1.f - fx) * (dy ? fy : 1.f - fy)
                         * (dz ? fz : 1.f - fz)
                       : 0.f;
            si[c] = grid[ok ? cell : 0];
        }
        const f32x4* fb = (const f32x4*)sfeats;
        const f32x4* fpc[8];
        float w8[8];
#pragma unroll
        for (int c = 0; c < 8; ++c) {
            bool hit = si[c] < n_sp;            // empty cell = 0x7fffffff
            w8[c]  = hit ? wc[c] : 0.f;
            fpc[c] = fb + (size_t)(hit ? si[c] : 0) * 8 + part * 4;
        }
        float acc[16];
#pragma unroll
        for (int k2 = 0; k2 < 16; ++k2) acc[k2] = 0.f;
#pragma unroll
        for (int c = 0; c < 8; ++c) {           // 32 f32x4 loads, batched
            f32x4 f0 = fpc[c][0], f1 = fpc[c][1], f2 = fpc[c][2], f3 = fpc[c][3];
            float w = w8[c];
#pragma unroll
            for (int k2 = 0; k2 < 4; ++k2) {
                acc[k2]      += w * f0[k2];
                acc[4 + k2]  += w * f1[k2];
                acc[8 + k2]  += w * f2[k2];
                acc[12 + k2] += w * f3[k2];
            }
        }
        int u = pl * 8 + 1 + j;
        _Float16* xp = hA + u * CS + part * 16;
        f16x8 h0, h1;
#pragma unroll
        for (int k2 = 0; k2 < 8; ++k2) { h0[k2] = (_Float16)acc[k2]; h1[k2] = (_Float16)acc[8 + k2]; }
        *(f16x8*)xp = h0;
        *(f16x8*)(xp + 8) = h1;
        f16x8 p0v, p1v;
#pragma unroll
        for (int k2 = 0; k2 < 4; ++k2) {
            p0v[k2]     = (_Float16)pf0[k2];
            p0v[4 + k2] = (_Float16)pf1[k2];
            p1v[k2]     = (_Float16)pf2[k2];
            p1v[4 + k2] = (_Float16)pf3[k2];
        }
        *(f16x8*)(hA + u * CS + 32 + part * 16) = p0v;
        *(f16x8*)(hA + u * CS + 40 + part * 16) = p1v;
    }
    __syncthreads();

    // ---- conv stack
    conv_layer<64,  6>(hA, w16_1, tv,       hB, tid);
    __syncthreads();
    conv_layer<128, 12>(hB, w16_2, tv + 128, hA, tid);
    __syncthreads();
    conv_layer<128, 12>(hA, w16_3, tv + 256, hB, tid);
    __syncthreads();

    // ---- layer 4 dot2 + in-wave shuffle softmax (point = 16 lanes, no LDS)
    {
        int col = tid >> 1, p4 = tid & 1;
        float sum = 0.f;
        if ((col & 7) != 7) {
#pragma unroll
            for (int t = 0; t < 3; ++t) {
                const _Float16* hp = hB + (col + t) * CS;
                const _Float16* wr = w4h + t * 128;
#pragma unroll
                for (int c8 = 0; c8 < 8; ++c8) {
                    int chunk = 2 * c8 + p4;          // bank-spread split
                    f16x8 h8 = *(const f16x8*)(hp + chunk * 8);
                    f16x8 w8 = *(const f16x8*)(wr + chunk * 8);
#pragma unroll
                    for (int p = 0; p < 4; ++p) {
                        f16x2 hv = { h8[2*p], h8[2*p+1] };
                        f16x2 wv = { w8[2*p], w8[2*p+1] };
#if __has_builtin(__builtin_amdgcn_fdot2)
                        sum = __builtin_amdgcn_fdot2(hv, wv, sum, false);
#else
                        sum += (float)hv[0]*(float)wv[0] + (float)hv[1]*(float)wv[1];
#endif
                    }
                }
            }
        }
        sum += __shfl_xor(sum, 1);                    // col total in both lanes
        float logit = sum + bias4[0];
        bool  dead  = (col & 7) == 7;
        float v = dead ? -1e30f : logit;
        v = fmaxf(v, __shfl_xor(v, 2));
        v = fmaxf(v, __shfl_xor(v, 4));
        v = fmaxf(v, __shfl_xor(v, 8));               // max over point's 7 cols
        float e = (!dead && p4 == 0) ? __expf(logit - v) : 0.f;
        float es = e;
        es += __shfl_xor(es, 2);
        es += __shfl_xor(es, 4);
        es += __shfl_xor(es, 8);                      // sum (even lanes valid)
        if (p4 == 0 && !dead) {
            int pgt = p0 + (col >> 3);
            if (pgt < N) out[(size_t)pgt * 7 + (col & 7)] = e / es;
        }
    }
}

// ---------------------------------------------------------------------------
extern "C" void kernel_launch(void* const* d_in, const int* in_sizes, int n_in,
                              void* d_out, int out_size, void* d_ws, size_t ws_size,
                              hipStream_t stream) {
    const int*   sparse_coords = (const int*)d_in[1];
    const int*   sparse_batch  = (const int*)d_in[2];
    const float* sparse_feats  = (const float*)d_in[3];
    const float* pdh           = (const float*)d_in[4];
    const float* ptsfeat       = (const float*)d_in[5];
    const int*   pts_batch     = (const int*)d_in[6];
    const float* w1 = (const float*)d_in[7];
    const float* g1 = (const float*)d_in[8],  *b1 = (const float*)d_in[9];
    const float* m1 = (const float*)d_in[10], *v1 = (const float*)d_in[11];
    const float* w2 = (const float*)d_in[12];
    const float* g2 = (const float*)d_in[13], *b2 = (const float*)d_in[14];
    const float* m2 = (const float*)d_in[15], *v2 = (const float*)d_in[16];
    const float* w3 = (const float*)d_in[17];
    const float* g3 = (const float*)d_in[18], *b3 = (const float*)d_in[19];
    const float* m3 = (const float*)d_in[20], *v3 = (const float*)d_in[21];
    const float* w4 = (const float*)d_in[22];
    const float* bias4 = (const float*)d_in[23];

    const int n_sp = in_sizes[2];
    const int N    = in_sizes[6];

    // workspace: [grid NG ints][minc 6][pad to 16B][w16_1|w16_2|w16_3][tvec]
    int* grid = (int*)d_ws;
    int* minc = grid + NG;
    _Float16* w16_1 = (_Float16*)((char*)d_ws + (size_t)(NG + 6) * 4 + 8);
    _Float16* w16_2 = w16_1 + 128 * 192;
    _Float16* w16_3 = w16_2 + 128 * 384;
    float*    tvec  = (float*)(w16_3 + 128 * 384);

    k_init<<<(NG / 4 + 255) / 256, 256, 0, stream>>>((int4*)grid, minc);
    k_scatter<<<(n_sp + 255) / 256, 256, 0, stream>>>(sparse_coords, sparse_batch,
                                                      n_sp, grid, minc);
    k_wconv<<<482, 256, 0, stream>>>(w1, w2, w3,
                                     g1, b1, m1, v1, g2, b2, m2, v2, g3, b3, m3, v3,
                                     w16_1, w16_2, w16_3, tvec);
    k_main<<<(N + PT - 1) / PT, 256, 0, stream>>>(
        pdh, ptsfeat, pts_batch, sparse_feats, grid, minc,
        w16_1, w16_2, w16_3, tvec, w4, bias4, (float*)d_out, N, n_sp);
}